// Round 1
// baseline (139.309 us; speedup 1.0000x reference)
//
#include <hip/hip_runtime.h>
#include <math.h>

#define PI_F     3.14159265358979f
#define TWOPI_F  6.283185307179586f
#define ALPHA_F  14.04f          // 2.34 * J, J = 6
#define NK       552960          // 720 * 768
#define NANG     720
#define NDET     768

// ---------- modified Bessel I0, Abramowitz-Stegun 9.8.1/9.8.2 (|eps|<2e-7 rel) ----
__device__ __forceinline__ float i0f(float x) {
    if (x < 3.75f) {
        float t = x * (1.0f / 3.75f);
        float t2 = t * t;
        return 1.0f + t2 * (3.5156229f + t2 * (3.0899424f + t2 * (1.2067492f +
                     t2 * (0.2659732f + t2 * (0.0360768f + t2 * 0.0045813f)))));
    } else {
        float ti = 3.75f / x;
        float p = 0.39894228f + ti * (0.01328592f + ti * (0.00225319f +
                  ti * (-0.00157565f + ti * (0.00916281f + ti * (-0.02057706f +
                  ti * (0.02635537f + ti * (-0.01647633f + ti * 0.00392377f)))))));
        return expf(x) * (1.0f / sqrtf(x)) * p;
    }
}

// multiply complex v by i^k
__device__ __forceinline__ float2 mul_ipow(float2 v, int k) {
    switch (k & 3) {
        case 0:  return v;
        case 1:  return make_float2(-v.y,  v.x);
        case 2:  return make_float2(-v.x, -v.y);
        default: return make_float2( v.y, -v.x);
    }
}

// ---------- Stockham radix-2 FFT in LDS (self-sorting, ping-pong) ------------------
// DIF form:  dst[q + s*2p] = a+b ;  dst[q + s*(2p+1)] = (a-b)*e^{sgn*2pi*p/n}
// Result ends in the returned pointer (== src buffer when log2(N) is even).
template<int N, bool INV>
__device__ __forceinline__ float2* stockham(float2* src, float2* dst, int tid, int T) {
    int n = N, log2s = 0;
    while (n > 1) {
        int h = n >> 1;
        int s = 1 << log2s;
        for (int i = tid; i < (N >> 1); i += T) {
            int q = i & (s - 1);
            int p = i >> log2s;
            float ang = (INV ? TWOPI_F : -TWOPI_F) * (float)p / (float)n;
            float sn, cs;
            sincosf(ang, &sn, &cs);
            float2 a = src[q + (p << log2s)];
            float2 b = src[q + ((p + h) << log2s)];
            float2 su = make_float2(a.x + b.x, a.y + b.y);
            float2 di = make_float2(a.x - b.x, a.y - b.y);
            dst[q + ((2 * p) << log2s)]     = su;
            dst[q + ((2 * p + 1) << log2s)] = make_float2(di.x * cs - di.y * sn,
                                                          di.x * sn + di.y * cs);
        }
        __syncthreads();
        float2* t = src; src = dst; dst = t;
        n = h; ++log2s;
    }
    return src;
}

// ---------- stage 0: apodization table (H=W=512, G=1024, same both dims) ----------
__global__ __launch_bounds__(512) void apod_kernel(float* __restrict__ apod) {
    int i = threadIdx.x;
    float n = (float)i - 256.0f;
    float u = n * (1.0f / 1024.0f);
    float pj = PI_F * 6.0f * u;
    float arg = ALPHA_F * ALPHA_F - pj * pj;
    float s = sqrtf(fabsf(arg) + 1e-20f);
    float F = (arg > 0.0f ? sinhf(s) / s : sinf(s) / s) * (6.0f / i0f(ALPHA_F));
    apod[i] = 1.0f / F;
}

// ---------- stage 1: row FFTs: U[r][k2] = i^k2 * sum_c a[r][c] W1024^{c k2} --------
__global__ __launch_bounds__(256) void fft_rows_kernel(const float* __restrict__ img,
                                                       const float* __restrict__ apod,
                                                       float2* __restrict__ U) {
    __shared__ float2 bA[1024], bB[1024];
    int r = blockIdx.x, t = threadIdx.x;
    float ar = apod[r];
    for (int c = t; c < 512; c += 256)
        bA[c] = make_float2(img[r * 512 + c] * ar * apod[c], 0.0f);
    for (int c = t + 512; c < 1024; c += 256)
        bA[c] = make_float2(0.0f, 0.0f);
    __syncthreads();
    float2* res = stockham<1024, false>(bA, bB, t, 256);
    for (int k = t; k < 1024; k += 256)
        U[r * 1024 + k] = mul_ipow(res[k], k);
}

// ---------- stage 2: col FFTs: GT[k2][k1] = i^k1/1024 * sum_r U[r][k2] W1024^{r k1}
// GT is grid_hat TRANSPOSED: GT[k2*1024 + k1] == grid_hat[k1][k2]
__global__ __launch_bounds__(256) void fft_cols_kernel(const float2* __restrict__ U,
                                                       float2* __restrict__ GT) {
    __shared__ float2 bA[1024], bB[1024];
    int k2 = blockIdx.x, t = threadIdx.x;
    for (int rr = t; rr < 512; rr += 256)
        bA[rr] = U[rr * 1024 + k2];
    for (int rr = t + 512; rr < 1024; rr += 256)
        bA[rr] = make_float2(0.0f, 0.0f);
    __syncthreads();
    float2* res = stockham<1024, false>(bA, bB, t, 256);
    const float sc = 1.0f / 1024.0f;
    for (int k1 = t; k1 < 1024; k1 += 256) {
        float2 v = mul_ipow(res[k1], k1);
        GT[k2 * 1024 + k1] = make_float2(v.x * sc, v.y * sc);
    }
}

// ---------- stage 3: KB-gridding gather: kdata[k] = sum_{a,b} GT[iy_b][ix_a] w1_a w2_b
__global__ __launch_bounds__(256) void gather_kernel(const float* __restrict__ ksp,
                                                     const float2* __restrict__ GT,
                                                     float2* __restrict__ KD) {
    int k = blockIdx.x * 256 + threadIdx.x;
    if (k >= NK) return;
    const float inv_i0a = 1.0f / i0f(ALPHA_F);
    float ky = ksp[k];
    float kx = ksp[NK + k];

    float w1[6], w2[6];
    int   i1[6], i2[6];

    // dim 1 (rows of grid_hat, from ky)
    {
        float v = (ky * 1024.0f) / TWOPI_F;
        v = fmodf(v, 1024.0f);
        if (v < 0.0f) v += 1024.0f;
        int base = (int)floorf(v);
        for (int j = 0; j < 6; ++j) {
            int p = base - 2 + j;
            float u = v - (float)p;
            float un = u * (1.0f / 3.0f);
            float x = fmaxf(1.0f - un * un, 0.0f);
            w1[j] = i0f(ALPHA_F * sqrtf(x)) * inv_i0a;
            i1[j] = (p + 1024) & 1023;
        }
    }
    // dim 2 (cols of grid_hat, from kx)
    {
        float v = (kx * 1024.0f) / TWOPI_F;
        v = fmodf(v, 1024.0f);
        if (v < 0.0f) v += 1024.0f;
        int base = (int)floorf(v);
        for (int j = 0; j < 6; ++j) {
            int p = base - 2 + j;
            float u = v - (float)p;
            float un = u * (1.0f / 3.0f);
            float x = fmaxf(1.0f - un * un, 0.0f);
            w2[j] = i0f(ALPHA_F * sqrtf(x)) * inv_i0a;
            i2[j] = (p + 1024) & 1023;
        }
    }

    float2 acc = make_float2(0.0f, 0.0f);
    for (int b = 0; b < 6; ++b) {
        const float2* row = GT + i2[b] * 1024;   // contiguous in i1 (k1)
        float wb = w2[b];
        for (int a = 0; a < 6; ++a) {
            float w = w1[a] * wb;
            float2 g = row[i1[a]];
            acc.x += w * g.x;
            acc.y += w * g.y;
        }
    }
    KD[k] = acc;
}

// ---------- stage 4: per-angle length-768 inverse FFT with shifts folded ----------
// out[n] = (-1)^n/768 * Re sum_m (-1)^m kdata[m] e^{+2pi i n m/768}
// 768 = 3*256: three 256-pt inverse FFTs + radix-3 twiddle combine.
__global__ __launch_bounds__(384) void ifft_rows_kernel(const float2* __restrict__ KD,
                                                        float* __restrict__ out) {
    __shared__ float2 fA[768], fB[768];
    int row = blockIdx.x, t = threadIdx.x;
    for (int m = t; m < 768; m += 384) {
        float2 c = KD[row * 768 + m];
        float sgn = (m & 1) ? -1.0f : 1.0f;
        int r = m % 3, tt = m / 3;                 // m = r + 3*tt
        fA[r * 256 + tt] = make_float2(c.x * sgn, c.y * sgn);
    }
    __syncthreads();
    int r = t >> 7, tl = t & 127;                  // 3 sub-FFTs x 128 threads
    float2* res = stockham<256, true>(fA + (r << 8), fB + (r << 8), tl, 128);
    float2* F = res - (r << 8);                    // same parity for all r (== fA)
    for (int n = t; n < 768; n += 384) {
        int p = n & 255;
        float2 F0 = F[p], F1 = F[256 + p], F2 = F[512 + p];
        float a1 = TWOPI_F * (float)n * (1.0f / 768.0f);
        float s1, c1, s2, c2;
        sincosf(a1, &s1, &c1);
        sincosf(2.0f * a1, &s2, &c2);
        float re = F0.x + (F1.x * c1 - F1.y * s1) + (F2.x * c2 - F2.y * s2);
        float scale = ((n & 1) ? -1.0f : 1.0f) * (1.0f / 768.0f);
        out[row * 768 + n] = re * scale;
    }
}

extern "C" void kernel_launch(void* const* d_in, const int* in_sizes, int n_in,
                              void* d_out, int out_size, void* d_ws, size_t ws_size,
                              hipStream_t stream) {
    (void)in_sizes; (void)n_in; (void)out_size; (void)ws_size;
    const float* image = (const float*)d_in[0];   // (1,1,512,512) f32
    const float* ksp   = (const float*)d_in[1];   // (2, 552960) f32

    float*  apod = (float*)d_ws;                              // 512 f32  @ 0
    float2* U    = (float2*)((char*)d_ws + 4096);             // 512*1024 c64 (4 MB)
    float2* GT   = U + 512 * 1024;                            // 1024*1024 c64 (8 MB)
    float2* KD   = GT + 1024 * 1024;                          // 552960 c64 (4.42 MB)
    float*  outp = (float*)d_out;

    hipLaunchKernelGGL(apod_kernel,      dim3(1),    dim3(512), 0, stream, apod);
    hipLaunchKernelGGL(fft_rows_kernel,  dim3(512),  dim3(256), 0, stream, image, apod, U);
    hipLaunchKernelGGL(fft_cols_kernel,  dim3(1024), dim3(256), 0, stream, U, GT);
    hipLaunchKernelGGL(gather_kernel,    dim3((NK + 255) / 256), dim3(256), 0, stream, ksp, GT, KD);
    hipLaunchKernelGGL(ifft_rows_kernel, dim3(NANG), dim3(384), 0, stream, KD, outp);
}

// Round 3
// 117.419 us; speedup vs baseline: 1.1864x; 1.1864x over previous
//
#include <hip/hip_runtime.h>
#include <math.h>

#define PI_F     3.14159265358979f
#define TWOPI_F  6.283185307179586f
#define ALPHA_F  14.04f          // 2.34 * J, J = 6
#define NK       552960          // 720 * 768
#define NANG     720
#define NDET     768

// ---------- modified Bessel I0, Abramowitz-Stegun 9.8.1/9.8.2 (|eps|<2e-7 rel) ----
__device__ __forceinline__ float i0f(float x) {
    if (x < 3.75f) {
        float t = x * (1.0f / 3.75f);
        float t2 = t * t;
        return 1.0f + t2 * (3.5156229f + t2 * (3.0899424f + t2 * (1.2067492f +
                     t2 * (0.2659732f + t2 * (0.0360768f + t2 * 0.0045813f)))));
    } else {
        float ti = 3.75f / x;
        float p = 0.39894228f + ti * (0.01328592f + ti * (0.00225319f +
                  ti * (-0.00157565f + ti * (0.00916281f + ti * (-0.02057706f +
                  ti * (0.02635537f + ti * (-0.01647633f + ti * 0.00392377f)))))));
        return __expf(x) * rsqrtf(x) * p;
    }
}

// image-domain apodization value for index i (N=512, G=1024): arg>0 always here
__device__ __forceinline__ float apodf(int i, float inv_i0a) {
    float u = ((float)i - 256.0f) * (1.0f / 1024.0f);
    float pj = PI_F * 6.0f * u;
    float arg = ALPHA_F * ALPHA_F - pj * pj;
    float s = sqrtf(arg);
    float F = sinhf(s) / s * (6.0f * inv_i0a);
    return 1.0f / F;
}

// multiply complex v by i^k
__device__ __forceinline__ float2 mul_ipow(float2 v, int k) {
    switch (k & 3) {
        case 0:  return v;
        case 1:  return make_float2(-v.y,  v.x);
        case 2:  return make_float2(-v.x, -v.y);
        default: return make_float2( v.y, -v.x);
    }
}

// ---------- batched Stockham radix-2 FFT in LDS with twiddle table ----------------
// B contiguous FFTs of length N (layout src[b*N + j]). tw[j] = e^{i*sgn*2pi*j/N},
// j < N/2. Result ends in returned pointer (== src when LOGN even).
template<int N, int LOGN, int B, int T>
__device__ __forceinline__ float2* stockham_b(float2* src, float2* dst,
                                              const float2* __restrict__ tw, int tid) {
    constexpr int HALF = N >> 1;
    int log2s = 0;
    for (int n = N; n > 1; n >>= 1, ++log2s) {
        int h = n >> 1;
        int s = 1 << log2s;
        #pragma unroll
        for (int i = tid; i < B * HALF; i += T) {
            int bb = i >> (LOGN - 1);
            int j  = i & (HALF - 1);
            int q = j & (s - 1);
            int p = j >> log2s;
            float2 w = tw[p << log2s];
            float2* S = src + bb * N;
            float2* D = dst + bb * N;
            float2 a  = S[q + (p << log2s)];
            float2 b2 = S[q + ((p + h) << log2s)];
            float2 su = make_float2(a.x + b2.x, a.y + b2.y);
            float2 di = make_float2(a.x - b2.x, a.y - b2.y);
            D[q + ((2 * p) << log2s)]     = su;
            D[q + ((2 * p + 1) << log2s)] = make_float2(di.x * w.x - di.y * w.y,
                                                        di.x * w.y + di.y * w.x);
        }
        __syncthreads();
        float2* t = src; src = dst; dst = t;
    }
    return src;
}

// ---------- stage 1: row FFTs (apod fused): U[r][k2]=i^k2 sum_c a[r][c] W^{c k2} ---
__global__ __launch_bounds__(256) void fft_rows_kernel(const float* __restrict__ img,
                                                       float2* __restrict__ U) {
    __shared__ float2 bA[1024], bB[1024], tw[512];
    int r = blockIdx.x, t = threadIdx.x;
    for (int j = t; j < 512; j += 256) {
        float ang = -TWOPI_F * (float)j * (1.0f / 1024.0f);
        float sn, cs; sincosf(ang, &sn, &cs);
        tw[j] = make_float2(cs, sn);
    }
    float inv_i0a = 1.0f / i0f(ALPHA_F);
    float ar = apodf(r, inv_i0a);
    for (int c = t; c < 512; c += 256)
        bA[c] = make_float2(img[r * 512 + c] * ar * apodf(c, inv_i0a), 0.0f);
    for (int c = t + 512; c < 1024; c += 256)
        bA[c] = make_float2(0.0f, 0.0f);
    __syncthreads();
    float2* res = stockham_b<1024, 10, 1, 256>(bA, bB, tw, t);
    for (int k = t; k < 1024; k += 256)
        U[r * 1024 + k] = mul_ipow(res[k], k);
}

// ---------- stage 2: col FFTs, 4 columns/block, coalesced --------------------------
// GT[k2*1024 + k1] == grid_hat[k1][k2] = i^k1/1024 * sum_r U[r][k2] W^{r k1}
__global__ __launch_bounds__(512) void fft_cols_kernel(const float2* __restrict__ U,
                                                       float2* __restrict__ GT) {
    __shared__ float2 bA[4096], bB[4096], tw[512];
    int c0 = blockIdx.x * 4, t = threadIdx.x;
    if (t < 512) {
        float ang = -TWOPI_F * (float)t * (1.0f / 1024.0f);
        float sn, cs; sincosf(ang, &sn, &cs);
        tw[t] = make_float2(cs, sn);
    }
    #pragma unroll
    for (int it = 0; it < 4; ++it) {               // rows 0..511, 4 cols: coalesced
        int i = t + it * 512;
        int rr = i >> 2, cc = i & 3;
        bA[cc * 1024 + rr] = U[rr * 1024 + c0 + cc];
    }
    #pragma unroll
    for (int it = 0; it < 4; ++it) {               // rows 512..1023: zero
        int i = t + it * 512;
        bA[(i >> 9) * 1024 + 512 + (i & 511)] = make_float2(0.0f, 0.0f);
    }
    __syncthreads();
    float2* res = stockham_b<1024, 10, 4, 512>(bA, bB, tw, t);
    const float sc = 1.0f / 1024.0f;
    #pragma unroll
    for (int it = 0; it < 8; ++it) {
        int i = t + it * 512;
        int cc = i >> 10, k1 = i & 1023;
        float2 v = mul_ipow(res[cc * 1024 + k1], k1);
        GT[(c0 + cc) * 1024 + k1] = make_float2(v.x * sc, v.y * sc);
    }
}

// ---------- stage 3: KB-gridding gather -------------------------------------------
__global__ __launch_bounds__(256) void gather_kernel(const float* __restrict__ ksp,
                                                     const float2* __restrict__ GT,
                                                     float2* __restrict__ KD) {
    int k = blockIdx.x * 256 + threadIdx.x;
    if (k >= NK) return;
    const float inv_i0a = 1.0f / i0f(ALPHA_F);
    float ky = ksp[k];
    float kx = ksp[NK + k];

    float w1[6], w2[6];
    int   i1[6], i2[6];

    {   // dim 1 (rows of grid_hat, from ky)
        float v = ky * (512.0f / PI_F);            // ky*1024/2pi
        float q = v * (1.0f / 1024.0f);
        v = (q - floorf(q)) * 1024.0f;             // mod 1024, in [0,1024)
        int base = (int)floorf(v);
        float frac = v - (float)base;
        #pragma unroll
        for (int j = 0; j < 6; ++j) {
            float u = frac + (float)(2 - j);
            float un = u * (1.0f / 3.0f);
            float x = fmaxf(1.0f - un * un, 0.0f);
            w1[j] = i0f(ALPHA_F * sqrtf(x)) * inv_i0a;
            i1[j] = (base - 2 + j + 1024) & 1023;
        }
    }
    {   // dim 2 (cols of grid_hat, from kx)
        float v = kx * (512.0f / PI_F);
        float q = v * (1.0f / 1024.0f);
        v = (q - floorf(q)) * 1024.0f;
        int base = (int)floorf(v);
        float frac = v - (float)base;
        #pragma unroll
        for (int j = 0; j < 6; ++j) {
            float u = frac + (float)(2 - j);
            float un = u * (1.0f / 3.0f);
            float x = fmaxf(1.0f - un * un, 0.0f);
            w2[j] = i0f(ALPHA_F * sqrtf(x)) * inv_i0a;
            i2[j] = (base - 2 + j + 1024) & 1023;
        }
    }

    float2 acc = make_float2(0.0f, 0.0f);
    #pragma unroll
    for (int b = 0; b < 6; ++b) {
        const float2* row = GT + i2[b] * 1024;     // contiguous in i1 (k1)
        float wb = w2[b];
        #pragma unroll
        for (int a = 0; a < 6; ++a) {
            float w = w1[a] * wb;
            float2 g = row[i1[a]];
            acc.x += w * g.x;
            acc.y += w * g.y;
        }
    }
    KD[k] = acc;
}

// ---------- stage 4: per-angle length-768 inverse FFT with shifts folded ----------
// out[n] = (-1)^n/768 * Re sum_m (-1)^m kdata[m] e^{+2pi i n m/768}
// 768 = 3*256: three 256-pt inverse FFTs + radix-3 twiddle combine.
__global__ __launch_bounds__(384) void ifft_rows_kernel(const float2* __restrict__ KD,
                                                        float* __restrict__ out) {
    __shared__ float2 fA[768], fB[768], tw[128];
    int row = blockIdx.x, t = threadIdx.x;
    if (t < 128) {
        float ang = TWOPI_F * (float)t * (1.0f / 256.0f);   // inverse sign
        float sn, cs; sincosf(ang, &sn, &cs);
        tw[t] = make_float2(cs, sn);
    }
    for (int m = t; m < 768; m += 384) {
        float2 c = KD[row * 768 + m];
        float sgn = (m & 1) ? -1.0f : 1.0f;
        int r = m % 3, tt = m / 3;                 // m = r + 3*tt
        fA[r * 256 + tt] = make_float2(c.x * sgn, c.y * sgn);
    }
    __syncthreads();
    float2* F = stockham_b<256, 8, 3, 384>(fA, fB, tw, t);
    for (int n = t; n < 768; n += 384) {
        int p = n & 255;
        float2 F0 = F[p], F1 = F[256 + p], F2 = F[512 + p];
        float a1 = TWOPI_F * (float)n * (1.0f / 768.0f);
        float s1, c1, s2, c2;
        __sincosf(a1, &s1, &c1);
        __sincosf(2.0f * a1, &s2, &c2);
        float re = F0.x + (F1.x * c1 - F1.y * s1) + (F2.x * c2 - F2.y * s2);
        float scale = ((n & 1) ? -1.0f : 1.0f) * (1.0f / 768.0f);
        out[row * 768 + n] = re * scale;
    }
}

extern "C" void kernel_launch(void* const* d_in, const int* in_sizes, int n_in,
                              void* d_out, int out_size, void* d_ws, size_t ws_size,
                              hipStream_t stream) {
    (void)in_sizes; (void)n_in; (void)out_size; (void)ws_size;
    const float* image = (const float*)d_in[0];   // (1,1,512,512) f32
    const float* ksp   = (const float*)d_in[1];   // (2, 552960) f32

    float2* U  = (float2*)d_ws;                   // 512*1024 c64  (4 MB)
    float2* GT = U + 512 * 1024;                  // 1024*1024 c64 (8 MB)
    float2* KD = GT + 1024 * 1024;                // 552960 c64    (4.42 MB)
    float*  outp = (float*)d_out;

    hipLaunchKernelGGL(fft_rows_kernel,  dim3(512),  dim3(256), 0, stream, image, U);
    hipLaunchKernelGGL(fft_cols_kernel,  dim3(256),  dim3(512), 0, stream, U, GT);
    hipLaunchKernelGGL(gather_kernel,    dim3((NK + 255) / 256), dim3(256), 0, stream, ksp, GT, KD);
    hipLaunchKernelGGL(ifft_rows_kernel, dim3(NANG), dim3(384), 0, stream, KD, outp);
}